// Round 21
// baseline (1063.196 us; speedup 1.0000x reference)
//
#include <hip/hip_runtime.h>
#include <hip/hip_bf16.h>
#include <cmath>

#define DD 1536
#define FF 6144

typedef __bf16 bf16_t;
typedef __bf16 bf16x8 __attribute__((ext_vector_type(8)));
typedef __bf16 bf16x4 __attribute__((ext_vector_type(4)));
typedef float  f32x4  __attribute__((ext_vector_type(4)));
typedef unsigned int u32x4 __attribute__((ext_vector_type(4)));

#define VM0 asm volatile("s_waitcnt vmcnt(0)" ::: "memory")
#define SB  __builtin_amdgcn_sched_barrier(0)
#define LGKM(N) do { asm volatile("s_waitcnt lgkmcnt(" #N ")" :::); SB; } while (0)
#define BAR __builtin_amdgcn_s_barrier()

__device__ __forceinline__ void async_load16(const bf16_t* g, bf16_t* l) {
  __builtin_amdgcn_global_load_lds(
      (const __attribute__((address_space(1))) void*)g,
      (__attribute__((address_space(3))) void*)l, 16, 0, 0);
}

// non-temporal 16B store (MUBUF nt): output streams bypass cache allocation so they
// don't evict L3-resident A/B panels (r20 PMC: 240MB fetch vs 44MB compulsory).
__device__ __forceinline__ void nt_store16(bf16_t* dst, bf16x8 v) {
  __builtin_nontemporal_store(*(u32x4*)&v, (u32x4*)dst);
}

// inline-asm LDS read: NOT ordered vs global_load_lds by the compiler; ordering is
// done explicitly via {vmcnt; barrier} (RAW) and counted lgkmcnt + sched_barrier (use).
__device__ __forceinline__ bf16x8 ds_read128(unsigned int addr) {
  bf16x8 r;
  asm volatile("ds_read_b128 %0, %1" : "=v"(r) : "v"(addr));
  return r;
}

// bijective XCD-aware remap (m204)
__device__ __forceinline__ void xcd_remap(int& bx, int& by) {
  const int gx = gridDim.x, gy = gridDim.y;
  int wg = by * gx + bx;
  const int nwg = gx * gy;
  const int q = nwg >> 3, r = nwg & 7, xcd = wg & 7, o = wg >> 3;
  wg = (xcd < r ? xcd * (q + 1) : r * (q + 1) + (xcd - r) * q) + o;
  bx = wg % gx;
  by = wg / gx;
}

// ---------------- weight fp32 -> bf16 transpose; optional per-K scale; output row stride ldt
__global__ __launch_bounds__(256) void transpose_to_bf16(
    const float* __restrict__ W, bf16_t* __restrict__ Wt, int K, int N,
    const float* __restrict__ s, int ldt) {
  __shared__ float tile[32][33];
  const int tx = threadIdx.x, ty = threadIdx.y;  // 32 x 8
  const int n0 = blockIdx.x * 32, k0 = blockIdx.y * 32;
#pragma unroll
  for (int i = 0; i < 4; i++)
    tile[ty + 8 * i][tx] = W[(size_t)(k0 + ty + 8 * i) * N + n0 + tx];
  __syncthreads();
  const float sc = (s != nullptr) ? s[k0 + tx] : 1.f;
#pragma unroll
  for (int i = 0; i < 4; i++)
    Wt[(size_t)(n0 + ty + 8 * i) * ldt + k0 + tx] = (bf16_t)(tile[tx][ty + 8 * i] * sc);
}

// ---------------- biasm = a + b ----------------
__global__ __launch_bounds__(256) void bias_add2(
    const float* __restrict__ a, const float* __restrict__ b, float* __restrict__ o, int n) {
  const int i = blockIdx.x * 256 + threadIdx.x;
  if (i < n) o[i] = a[i] + b[i];
}

// ---------------- reduction helpers ----------------
__device__ __forceinline__ void breduce1(float& a) {
#pragma unroll
  for (int off = 32; off; off >>= 1) a += __shfl_xor(a, off);
  __shared__ float sa[4];
  const int w = threadIdx.x >> 6, ln = threadIdx.x & 63;
  if (ln == 0) sa[w] = a;
  __syncthreads();
  a = (sa[0] + sa[1]) + (sa[2] + sa[3]);
  __syncthreads();
}

__device__ __forceinline__ void breduce2(float& a, float& b) {
#pragma unroll
  for (int off = 32; off; off >>= 1) {
    a += __shfl_xor(a, off);
    b += __shfl_xor(b, off);
  }
  __shared__ float sa[4], sb[4];
  const int w = threadIdx.x >> 6, ln = threadIdx.x & 63;
  if (ln == 0) { sa[w] = a; sb[w] = b; }
  __syncthreads();
  a = (sa[0] + sa[1]) + (sa[2] + sa[3]);
  b = (sb[0] + sb[1]) + (sb[2] + sb[3]);
  __syncthreads();
}

// ---------------- x: xr = x*rq (bf16) + rqinv[row] = sqrt(ms+eps) ----------------
__global__ __launch_bounds__(256) void norm_x1(
    const float* __restrict__ x, bf16_t* __restrict__ xr, float* __restrict__ rqinv) {
  const int row = blockIdx.x, t = threadIdx.x;
  const float* p = x + (size_t)row * DD;
  f32x4 v0 = ((const f32x4*)p)[t];
  f32x4 v1 = 0.0f;
  if (t < 128) v1 = ((const f32x4*)p)[256 + t];
  float s2 = 0.f;
#pragma unroll
  for (int e = 0; e < 4; e++) s2 += v0[e] * v0[e];
  if (t < 128) {
#pragma unroll
    for (int e = 0; e < 4; e++) s2 += v1[e] * v1[e];
  }
  breduce1(s2);
  const float ms = s2 * (1.f / DD) + 1e-7f;
  const float rq = rsqrtf(ms);
  if (t == 0) rqinv[row] = sqrtf(ms);
  auto emit = [&](int ci, f32x4 v) {
    bf16x4 orr;
#pragma unroll
    for (int e = 0; e < 4; e++) orr[e] = (bf16_t)(v[e] * rq);
    *(bf16x4*)(xr + (size_t)row * DD + ci * 4) = orr;
  };
  emit(t, v0);
  if (t < 128) emit(256 + t, v1);
}

// ---------------- LayerNorm -> bf16 ----------------
__global__ __launch_bounds__(256) void norm_ln(
    const float* __restrict__ x, const float* __restrict__ w,
    const float* __restrict__ bb, bf16_t* __restrict__ o) {
  const int row = blockIdx.x, t = threadIdx.x;
  const float* p = x + (size_t)row * DD;
  f32x4 v0 = ((const f32x4*)p)[t];
  f32x4 v1 = 0.0f;
  if (t < 128) v1 = ((const f32x4*)p)[256 + t];
  float s = 0.f, s2 = 0.f;
#pragma unroll
  for (int e = 0; e < 4; e++) { s += v0[e]; s2 += v0[e] * v0[e]; }
  if (t < 128) {
#pragma unroll
    for (int e = 0; e < 4; e++) { s += v1[e]; s2 += v1[e] * v1[e]; }
  }
  breduce2(s, s2);
  const float mu = s * (1.f / DD);
  const float rln = rsqrtf(s2 * (1.f / DD) - mu * mu + 1e-5f);
  auto emit = [&](int ci, f32x4 v) {
    const int i0 = ci * 4;
    bf16x4 ov;
#pragma unroll
    for (int e = 0; e < 4; e++)
      ov[e] = (bf16_t)((v[e] - mu) * rln * w[i0 + e] + bb[i0 + e]);
    *(bf16x4*)(o + (size_t)row * DD + i0) = ov;
  };
  emit(t, v0);
  if (t < 128) emit(256 + t, v1);
}

// ---------------- text: Tb = raw bf16, Tck = text*rtq ----------
__global__ __launch_bounds__(256) void norm_t2(
    const float* __restrict__ te, bf16_t* __restrict__ tb, bf16_t* __restrict__ tck) {
  const int row = blockIdx.x, t = threadIdx.x;
  const float* p = te + (size_t)row * DD;
  f32x4 v0 = ((const f32x4*)p)[t];
  f32x4 v1 = 0.0f;
  if (t < 128) v1 = ((const f32x4*)p)[256 + t];
  float s2 = 0.f;
#pragma unroll
  for (int e = 0; e < 4; e++) s2 += v0[e] * v0[e];
  if (t < 128) {
#pragma unroll
    for (int e = 0; e < 4; e++) s2 += v1[e] * v1[e];
  }
  breduce1(s2);
  const float rq = rsqrtf(s2 * (1.f / DD) + 1e-7f);
  auto emit = [&](int ci, f32x4 v) {
    bf16x4 ob, oc;
#pragma unroll
    for (int e = 0; e < 4; e++) {
      ob[e] = (bf16_t)v[e];
      oc[e] = (bf16_t)(v[e] * rq);
    }
    const size_t o = (size_t)row * DD + ci * 4;
    *(bf16x4*)(tb + o) = ob;
    *(bf16x4*)(tck + o) = oc;
  };
  emit(t, v0);
  if (t < 128) emit(256 + t, v1);
}

// ---------------- in-place bf16 row softmax ----------------
template <int NC>
__global__ __launch_bounds__(256) void softmax_bf16(bf16_t* __restrict__ S) {
  const int t = threadIdx.x;
  bf16_t* sr = S + (size_t)blockIdx.x * NC;
  constexpr int NV = (NC / 8 + 255) / 256;
  float v[NV][8];
  float mx = -3.4e38f;
#pragma unroll
  for (int i = 0; i < NV; i++) {
    const int idx = t + i * 256;
    if (idx * 8 < NC) {
      bf16x8 b = ((const bf16x8*)sr)[idx];
#pragma unroll
      for (int e = 0; e < 8; e++) {
        v[i][e] = (float)b[e];
        mx = fmaxf(mx, v[i][e]);
      }
    }
  }
#pragma unroll
  for (int off = 32; off; off >>= 1) mx = fmaxf(mx, __shfl_xor(mx, off));
  __shared__ float sm[4];
  const int w = t >> 6, ln = t & 63;
  if (ln == 0) sm[w] = mx;
  __syncthreads();
  mx = fmaxf(fmaxf(sm[0], sm[1]), fmaxf(sm[2], sm[3]));
  __syncthreads();
  float sum = 0.f;
#pragma unroll
  for (int i = 0; i < NV; i++) {
    const int idx = t + i * 256;
    if (idx * 8 < NC) {
#pragma unroll
      for (int e = 0; e < 8; e++) {
        v[i][e] = __expf(v[i][e] - mx);
        sum += v[i][e];
      }
    }
  }
#pragma unroll
  for (int off = 32; off; off >>= 1) sum += __shfl_xor(sum, off);
  __shared__ float ss[4];
  if (ln == 0) ss[w] = sum;
  __syncthreads();
  sum = (ss[0] + ss[1]) + (ss[2] + ss[3]);
  const float inv = 1.f / sum;
#pragma unroll
  for (int i = 0; i < NV; i++) {
    const int idx = t + i * 256;
    if (idx * 8 < NC) {
      bf16x8 o;
#pragma unroll
      for (int e = 0; e < 8; e++) o[e] = (bf16_t)(v[i][e] * inv);
      ((bf16x8*)sr)[idx] = o;
    }
  }
}

enum { EPI_BF16 = 0, EPI_F32_SCALE = 1, EPI_ADD_X = 2, EPI_ACC = 3, EPI_GELU = 4, EPI_TRANS = 5, EPI_BF16S = 6, EPI_PROJ3 = 7 };

template <int EPI>
__device__ __forceinline__ void epi_frag(
    f32x4 v, int r0, int c, const float* bias, void* Cout, const float* Xres,
    int ldc, float scale, int t_ld, int t_bshift, size_t t_bstride) {
  const float bv = (bias != nullptr) ? bias[c] : 0.f;
  if constexpr (EPI == EPI_BF16) {
    bf16_t* C = (bf16_t*)Cout;
#pragma unroll
    for (int r = 0; r < 4; r++) C[(size_t)(r0 + r) * ldc + c] = (bf16_t)(v[r] + bv);
  } else if constexpr (EPI == EPI_F32_SCALE) {
    float* C = (float*)Cout;
#pragma unroll
    for (int r = 0; r < 4; r++) C[(size_t)(r0 + r) * ldc + c] = v[r] * scale;
  } else if constexpr (EPI == EPI_BF16S) {
    bf16_t* C = (bf16_t*)Cout;
#pragma unroll
    for (int r = 0; r < 4; r++) C[(size_t)(r0 + r) * ldc + c] = (bf16_t)(v[r] * scale);
  } else if constexpr (EPI == EPI_ADD_X) {
    float* C = (float*)Cout;
#pragma unroll
    for (int r = 0; r < 4; r++) {
      const size_t ix = (size_t)(r0 + r) * ldc + c;
      C[ix] = Xres[ix] + v[r] + bv;
    }
  } else if constexpr (EPI == EPI_ACC) {
    float* C = (float*)Cout;
#pragma unroll
    for (int r = 0; r < 4; r++) {
      const size_t ix = (size_t)(r0 + r) * ldc + c;
      C[ix] += v[r] + bv;
    }
  } else if constexpr (EPI == EPI_GELU) {
    bf16_t* C = (bf16_t*)Cout;
#pragma unroll
    for (int r = 0; r < 4; r++) {
      const float h = v[r] + bv;
      C[(size_t)(r0 + r) * ldc + c] = (bf16_t)(0.5f * h * (1.f + erff(h * 0.70710678118654752f)));
    }
  } else if constexpr (EPI == EPI_TRANS) {  // batched C^T: out[b][c][n]
    const int b = r0 >> t_bshift;
    const int n = r0 & ((1 << t_bshift) - 1);
    bf16_t* C = (bf16_t*)Cout + (size_t)b * t_bstride + (size_t)c * t_ld + n;
    bf16x4 o;
#pragma unroll
    for (int r = 0; r < 4; r++) o[r] = (bf16_t)(v[r] + bv);
    *(bf16x4*)C = o;
  }
}

// ---------------- gemm_bt: 128x128 tile, 4 waves, BK=32 (proven r2 kernel + batch-B) ------
template <int EPI>
__global__ __launch_bounds__(256) void gemm_bt(
    const bf16_t* __restrict__ A, const bf16_t* __restrict__ B,
    const float* __restrict__ bias, void* __restrict__ Cout,
    const float* __restrict__ Xres,
    int nK, int lda, int ldb, int ldc, float scale,
    int bsh, size_t bstr, int t_ld, int t_bshift, size_t t_bstride) {
  __shared__ __align__(16) bf16_t As[2][128 * 32];
  __shared__ __align__(16) bf16_t Bs[2][128 * 32];
  const int tid = threadIdx.x;
  int bx = blockIdx.x, by = blockIdx.y;
  xcd_remap(bx, by);
  const int m0 = by * 128, n0 = bx * 128;
  const int wave = tid >> 6, lane = tid & 63, l15 = lane & 15, hi = lane >> 4;
  const int wm = wave >> 1, wn = wave & 1;
  const int srow = tid >> 2, scol = (tid & 3) << 3;

  const bf16_t* Bb = bsh ? (B + (size_t)(m0 >> bsh) * bstr) : B;
  const bf16_t* ga = A + (size_t)(m0 + srow) * lda + scol;
  const bf16_t* gb = Bb + (size_t)(n0 + srow) * ldb + scol;
  const int lo = wave * 512;

  f32x4 acc[4][4];
#pragma unroll
  for (int i = 0; i < 4; i++)
#pragma unroll
    for (int j = 0; j < 4; j++) acc[i][j] = 0.0f;

  auto stage = [&](int buf, int kt) {
    const bf16_t* a = ga + (size_t)kt * 32;
    const bf16_t* b = gb + (size_t)kt * 32;
    async_load16(a, &As[buf][lo]);
    async_load16(a + (size_t)64 * lda, &As[buf][2048 + lo]);
    async_load16(b, &Bs[buf][lo]);
    async_load16(b + (size_t)64 * ldb, &Bs[buf][2048 + lo]);
  };

  auto compute = [&](int buf) {
    bf16x8 af[4], bg[4];
#pragma unroll
    for (int i = 0; i < 4; i++)
      af[i] = *(const bf16x8*)&As[buf][(wm * 64 + i * 16 + l15) * 32 + hi * 8];
#pragma unroll
    for (int j = 0; j < 4; j++)
      bg[j] = *(const bf16x8*)&Bs[buf][(wn * 64 + j * 16 + l15) * 32 + hi * 8];
#pragma unroll
    for (int i = 0; i < 4; i++)
#pragma unroll
      for (int j = 0; j < 4; j++)
        acc[i][j] = __builtin_amdgcn_mfma_f32_16x16x32_bf16(af[i], bg[j], acc[i][j], 0, 0, 0);
  };

  stage(0, 0);
  __syncthreads();
  for (int kt = 0; kt < nK; ++kt) {
    if (kt + 1 < nK) stage((kt + 1) & 1, kt + 1);
    compute(kt & 1);
    __syncthreads();
  }

#pragma unroll
  for (int i = 0; i < 4; i++) {
    const int r0 = m0 + wm * 64 + i * 16 + hi * 4;
#pragma unroll
    for (int j = 0; j < 4; j++) {
      const int c = n0 + wn * 64 + j * 16 + l15;
      epi_frag<EPI>(acc[i][j], r0, c, bias, Cout, Xres, ldc, scale, t_ld, t_bshift, t_bstride);
    }
  }
}

// ---------------- gemm8: 256 x (NF*64) tile, 8 waves, BK=64, single-barrier K-tile --------
// K-loop identical to r19/r20 (verified 1042us). r20's LDS-staged coalesced bf16
// epilogue retained (full-line stores). r21: those stores are now NON-TEMPORAL
// (MUBUF nt) — r20 PMC falsified the RFO theory (FETCH unchanged at 240MB with
// coalesced stores); revised theory: the ~98MB output stream evicts L3-resident
// A/B panels (compulsory 44MB vs measured 240MB fetch). NT stores keep the output
// stream out of the cache hierarchy so panels stay resident. fp32 RMW epilogues
// (ADD_X/ACC) keep normal caching (their output is re-read).
template <int EPI, int NF>
__global__ __launch_bounds__(512, 2) void gemm8(
    const bf16_t* __restrict__ A, const bf16_t* __restrict__ B,
    const float* __restrict__ bias, void* __restrict__ Cout,
    const float* __restrict__ Xres,
    int nT, int lda, int ldb, int ldc, float scale,
    int bsh, size_t bstr, int t_ld, int t_bshift, size_t t_bstride) {
  constexpr int NB = NF * 64;   // B-tile rows (output cols per block)
  __shared__ __align__(16) bf16_t lds[32768 + 2 * NB * 64];  // As[2] | Bs[2]; reused as C-tile
  const int tid = threadIdx.x;
  int bx = blockIdx.x, by = blockIdx.y;
  xcd_remap(bx, by);
  const int m0 = by * 256, n0 = bx * NB;
  const int wave = tid >> 6, lane = tid & 63, l15 = lane & 15, hi = lane >> 4;
  const int wm = wave >> 2, wn = wave & 3;  // 2 x 4 waves; per-wave 128 x NF*16 output

  const int srow = tid >> 3;
  const int scol = ((tid & 7) ^ (srow & 7)) << 3;
  const bf16_t* Bb = bsh ? (B + (size_t)(m0 >> bsh) * bstr) : B;
  const bf16_t* gA = A + (size_t)(m0 + srow) * lda + scol;
  const bf16_t* gB = Bb + (size_t)(n0 + srow) * ldb + scol;
  const int ldst = wave * 512;

  // per-lane ds_read byte bases (buf 0); A buf1 = +32768 B, B buf1 = +NB*128 B
  const unsigned swz0 = (unsigned)(((hi ^ (l15 & 7)) << 3) * 2);
  const unsigned swz1 = (unsigned)((((hi + 4) ^ (l15 & 7)) << 3) * 2);
  const unsigned aBase = (unsigned)(size_t)&lds[0] + (unsigned)((wm * 128 + l15) * 128);
  const unsigned bBase = (unsigned)(size_t)&lds[0] + 65536u + (unsigned)((wn * NF * 16 + l15) * 128);
  const unsigned a0 = aBase + swz0, a1 = aBase + swz1;
  const unsigned b0 = bBase + swz0, b1 = bBase + swz1;

  f32x4 acc[8][NF];
#pragma unroll
  for (int i = 0; i < 8; i++)
#pragma unroll
    for (int j = 0; j < NF; j++) acc[i][j] = 0.0f;

  auto stgA = [&](int t) {
    if (t >= nT) return;
    const int buf = t & 1;
    const size_t kof = (size_t)t * 64;
#pragma unroll
    for (int g = 0; g < 4; g++)
      async_load16(gA + (size_t)(g * 64) * lda + kof, &lds[buf * 16384 + g * 4096 + ldst]);
  };
  auto stgB = [&](int t) {
    if (t >= nT) return;
    const int buf = t & 1;
    const size_t kof = (size_t)t * 64;
#pragma unroll
    for (int g = 0; g < NF; g++)
      async_load16(gB + (size_t)(g * 64) * ldb + kof, &lds[32768 + buf * (NB * 64) + g * 4096 + ldst]);
  };

  bf16x8 af[4][2], bg[NF][2];
  auto LDA = [&](int buf, int mh) {
#pragma unroll
    for (int i = 0; i < 4; i++) {
      const unsigned d = (unsigned)(buf * 32768 + (mh * 4 + i) * 2048);
      af[i][0] = ds_read128(a0 + d);
      af[i][1] = ds_read128(a1 + d);
    }
  };
  auto LDBf = [&](int buf, int fj) {
    const unsigned d = (unsigned)(buf * (NB * 128) + fj * 2048);
    bg[fj][0] = ds_read128(b0 + d);
    bg[fj][1] = ds_read128(b1 + d);
  };
  auto MMf = [&](int mh, int fj) {
    __builtin_amdgcn_s_setprio(1);
#pragma unroll
    for (int i = 0; i < 4; i++)
#pragma unroll
      for (int ks = 0; ks < 2; ks++)
        acc[mh * 4 + i][fj] = __builtin_amdgcn_mfma_f32_16x16x32_bf16(
            af[i][ks], bg[fj][ks], acc[mh * 4 + i][fj], 0, 0, 0);
    __builtin_amdgcn_s_setprio(0);
  };

  // one K-tile iteration; buf is a compile-time literal at each call site
  auto iter = [&](int k, int buf) {
    VM0;   // per-wave: own tile-k loads (issued last iter) drained
    BAR;   // globalize drain (RAW) + all waves' buf^1 reads done (WAR)
    stgB(k + 1);
    stgA(k + 1);
    LDA(buf, 0);
#pragma unroll
    for (int fj = 0; fj < NF; fj++) LDBf(buf, fj);
    SB;
    if constexpr (NF == 4) {  // byte-exact r15 wait sequence
      LGKM(4);  MMf(0, 0); MMf(0, 1);
      LGKM(0);  MMf(0, 2); MMf(0, 3);
    } else {                  // NF == 3: same ledger, finer counted waits
      LGKM(4);  MMf(0, 0);
      LGKM(2);  MMf(0, 1);
      LGKM(0);  MMf(0, 2);
    }
    LDA(buf, 1);   // re-issue af <- mh1 (consumers of af0 already issued)
    SB;
    LGKM(0);
#pragma unroll
    for (int fj = 0; fj < NF; fj++) MMf(1, fj);
  };

  // prologue: stage tile 0
  stgB(0);
  stgA(0);

  for (int k = 0; k < nT; k += 2) {  // nT is even for all call sites
    iter(k, 0);
    iter(k + 1, 1);
  }

  if constexpr (EPI == EPI_ADD_X || EPI == EPI_ACC || EPI == EPI_F32_SCALE) {
    // fp32 direct path (stores are already full-line; output re-read -> keep cached)
#pragma unroll
    for (int fi = 0; fi < 8; fi++) {
      const int r0 = m0 + wm * 128 + fi * 16 + hi * 4;
#pragma unroll
      for (int fj = 0; fj < NF; fj++) {
        const int c = n0 + wn * NF * 16 + fj * 16 + l15;
        epi_frag<EPI>(acc[fi][fj], r0, c, bias, Cout, Xres, ldc, scale, t_ld, t_bshift, t_bstride);
      }
    }
  } else {
    // -------- LDS-staged coalesced bf16 epilogue (non-temporal stores) --------
    __syncthreads();   // all waves done with staging LDS (reads drained per-wave; no DMA in flight)
    const bool vreg = (EPI == EPI_PROJ3) && (n0 < 1536);   // block-uniform
    // write phase: fragment -> LDS tile (V-region: transposed [c][n], else row-major [row][NB])
#pragma unroll
    for (int fi = 0; fi < 8; fi++) {
      const int rl = wm * 128 + fi * 16 + hi * 4;   // local row 0..255
#pragma unroll
      for (int fj = 0; fj < NF; fj++) {
        const int cl = wn * NF * 16 + fj * 16 + l15;  // local col 0..NB-1
        const int cg = n0 + cl;
        const float bv = (bias != nullptr) ? bias[cg] : 0.f;
        f32x4 v = acc[fi][fj];
#pragma unroll
        for (int r = 0; r < 4; r++) {
          bf16_t ov;
          if constexpr (EPI == EPI_GELU) {
            const float h = v[r] + bv;
            ov = (bf16_t)(0.5f * h * (1.f + erff(h * 0.70710678118654752f)));
          } else if constexpr (EPI == EPI_BF16S) {
            ov = (bf16_t)(v[r] * scale);
          } else if constexpr (EPI == EPI_PROJ3) {
            ov = vreg ? (bf16_t)(v[r] * Xres[m0 + rl + r] + bv) : (bf16_t)(v[r] + bv);
          } else {  // EPI_BF16
            ov = (bf16_t)(v[r] + bv);
          }
          if (vreg) lds[cl * 256 + rl + r] = ov;
          else      lds[(rl + r) * NB + cl] = ov;
        }
      }
    }
    __syncthreads();
    // copy phase: linear LDS -> coalesced NON-TEMPORAL global dwordx4
    if (!vreg) {
      constexpr int CPR = NB / 8;                 // 16B chunks per row
      constexpr int ITERS = (256 * NB) / (512 * 8);
#pragma unroll
      for (int it = 0; it < ITERS; ++it) {
        const int idx = it * 512 + tid;
        const int row = idx / CPR, c8 = idx % CPR;
        bf16x8 val = *(bf16x8*)&lds[row * NB + c8 * 8];
        bf16_t* dst;
        if constexpr (EPI == EPI_PROJ3) {
          bf16_t* base = (bf16_t*)Cout;
          if (n0 < 4608) dst = base + (size_t)(m0 + row) * 3072 + (n0 - 1536) + c8 * 8;
          else dst = base + 37748736 + (size_t)(m0 + row) * 1536 + (n0 - 4608) + c8 * 8;
        } else {
          dst = (bf16_t*)Cout + (size_t)(m0 + row) * ldc + n0 + c8 * 8;
        }
        nt_store16(dst, val);
      }
    } else {
      // V region (PROJ3, NB==256): lds is [c][n] 256x256; rows contiguous in n
      const int b = m0 >> 12, nbase = m0 & 4095;
#pragma unroll
      for (int it = 0; it < 16; ++it) {
        const int idx = it * 512 + tid;
        const int c = idx >> 5, n8 = idx & 31;
        bf16x8 val = *(bf16x8*)&lds[c * 256 + n8 * 8];
        bf16_t* dst = (bf16_t*)Cout + 25165824 + (size_t)b * ((size_t)DD * 4096)
                      + (size_t)(n0 + c) * 4096 + nbase + n8 * 8;
        nt_store16(dst, val);
      }
    }
  }
}

// ---------------- host ----------------
extern "C" void kernel_launch(void* const* d_in, const int* in_sizes, int n_in,
                              void* d_out, int out_size, void* d_ws, size_t ws_size,
                              hipStream_t stream) {
  (void)in_sizes; (void)n_in; (void)out_size; (void)ws_size;
  const float* x   = (const float*)d_in[0];
  const float* te  = (const float*)d_in[1];
  const float* sqw = (const float*)d_in[2];
  const float* skw = (const float*)d_in[3];
  const float* cqw = (const float*)d_in[4];
  const float* ckw = (const float*)d_in[5];
  const float* lnw = (const float*)d_in[6];
  const float* lnb = (const float*)d_in[7];
  const float* Wq = (const float*)d_in[8];  const float* bq = (const float*)d_in[9];
  const float* Wk = (const float*)d_in[10]; const float* bk = (const float*)d_in[11];
  const float* Wv = (const float*)d_in[12]; const float* bv = (const float*)d_in[13];
  const float* Wo = (const float*)d_in[14]; const float* bo = (const float*)d_in[15];
  const float* CWq = (const float*)d_in[16]; const float* Cbq = (const float*)d_in[17];
  const float* CWk = (const float*)d_in[18]; const float* Cbk = (const float*)d_in[19];
  const float* CWv = (const float*)d_in[20]; const float* Cbv = (const float*)d_in[21];
  const float* CWo = (const float*)d_in[22]; const float* Cbo = (const float*)d_in[23];
  const float* W1 = (const float*)d_in[24]; const float* b1 = (const float*)d_in[25];
  const float* W2 = (const float*)d_in[26]; const float* b2 = (const float*)d_in[27];
  float* out = (float*)d_out;

  // ---- arena (bf16 el offsets); peak ~170 MB ----
  bf16_t* ws = (bf16_t*)d_ws;
  bf16_t* R0 = ws;                  // 9437184: [Wv|Wq|Wk|CWq]^T -> {CK,CVt,Sc} -> W1^T
  bf16_t* R1 = ws + 9437184;        // 9437184: CWk/CWv^T -> [Wo|CWo]^T -> W2^T
  bf16_t* R2 = ws + 18874368;       // 12582912: xr -> LNo
  bf16_t* Tb  = ws + 31457280;      // 1572864
  bf16_t* Tck = ws + 33030144;      // 1572864
  bf16_t* R4 = ws + 34603008;       // 25165824: Q|K(ldc3072) -> concat APre|CPre -> H[0:..]
  bf16_t* R5 = ws + 59768832;       // 12582912: V^T -> H mid   (= R4 + 25165824)
  bf16_t* R6 = ws + 72351744;       // 12582912: CQ -> H end    (= R4 + 37748736)
  bf16_t* S  = ws;                  // 33554432 overlay (self-attn scores)
  float* bcat4 = (float*)(ws + 84934656);    // 6144 f32 = [bv|bq|bk|Cbq]
  float* biasm = (float*)(ws + 84946944);    // 1536 f32 = bo+Cbo
  float* rqinv = (float*)(ws + 84950016);    // 8192 f32
  bf16_t* CK  = R0;
  bf16_t* CVt = R0 + 1572864;
  bf16_t* Sc  = R0 + 3145728;       // 8192x512 bf16
  bf16_t* H   = R4;                 // 8192x6144 (R4+R5+R6 contiguous)

  const dim3 blk(256), blk8(512), tb(32, 8);
  const float scl = 0.025515518153991442f;  // 1/sqrt(1536)

  auto T = [&](const float* W, bf16_t* Wt, int K, int N, const float* s, int ldt) {
    transpose_to_bf16<<<dim3(N / 32, K / 32), tb, 0, stream>>>(W, Wt, K, N, s, ldt);
  };
  auto g8 = [](int M, int N) { return dim3(N / 256, M / 256); };   // NF=4 grids
  auto g6 = [](int M, int N) { return dim3(N / 192, M / 256); };   // NF=3 grids
  auto g4 = [](int M, int N) { return dim3(N / 128, M / 128); };

  // biases
  hipMemcpyAsync(bcat4,        bv,  DD * sizeof(float), hipMemcpyDeviceToDevice, stream);
  hipMemcpyAsync(bcat4 + DD,   bq,  DD * sizeof(float), hipMemcpyDeviceToDevice, stream);
  hipMemcpyAsync(bcat4 + 2*DD, bk,  DD * sizeof(float), hipMemcpyDeviceToDevice, stream);
  hipMemcpyAsync(bcat4 + 3*DD, Cbq, DD * sizeof(float), hipMemcpyDeviceToDevice, stream);
  bias_add2<<<6, blk, 0, stream>>>(bo, Cbo, biasm, DD);

  // norm: xr + per-row descale
  norm_x1<<<8192, blk, 0, stream>>>(x, R2, rqinv);

  // mega-projection: [V^T | Q|K | CQ] = xr @ [Wv | Wq*sqw | Wk*skw | CWq*cqw]^T, N=6144
  T(Wv,  R0,               DD, DD, nullptr, DD);
  T(Wq,  R0 + 2359296,     DD, DD, sqw,     DD);
  T(Wk,  R0 + 4718592,     DD, DD, skw,     DD);
  T(CWq, R0 + 7077888,     DD, DD, cqw,     DD);
  gemm8<EPI_PROJ3, 4><<<g8(8192, FF), blk8, 0, stream>>>(R2, R0, bcat4, R4, rqinv,
      24, DD, DD, 3072, 1.f, 0, 0, 0, 0, 0);

  // self-attention (batched over 2 via m0>>12)
  gemm8<EPI_BF16S, 4><<<g8(8192, 4096), blk8, 0, stream>>>(R4 /*Q*/, R4 + DD /*K*/, nullptr, S, nullptr,
      24, 3072, 3072, 4096, scl, 12, (size_t)4096 * 3072, 0, 0, 0);
  softmax_bf16<4096><<<8192, blk, 0, stream>>>(S);
  gemm8<EPI_BF16, 3><<<g6(8192, DD), blk8, 0, stream>>>(S, R5, nullptr, R4, nullptr,
      64, 4096, 4096, 3072, 1.f, 12, (size_t)DD * 4096, 0, 0, 0);

  // cross-attention
  norm_t2<<<1024, blk, 0, stream>>>(te, Tb, Tck);
  T(CWk, R1, DD, DD, ckw, DD);
  gemm_bt<EPI_BF16><<<g4(1024, DD), blk, 0, stream>>>(Tck, R1, Cbk, CK, nullptr,
      48, DD, DD, DD, 1.f, 0, 0, 0, 0, 0);
  T(CWv, R1 + 2359296, DD, DD, nullptr, DD);
  gemm_bt<EPI_TRANS><<<g4(1024, DD), blk, 0, stream>>>(Tb, R1 + 2359296, Cbv, CVt, nullptr,
      48, DD, DD, 0, 1.f, 0, 0, 512, 9, (size_t)DD * 512);
  gemm_bt<EPI_BF16S><<<g4(8192, 512), blk, 0, stream>>>(R6 /*CQ*/, CK, nullptr, Sc, nullptr,
      48, DD, DD, 512, scl, 12, (size_t)512 * DD, 0, 0, 0);
  softmax_bf16<512><<<8192, blk, 0, stream>>>(Sc);
  gemm8<EPI_BF16, 3><<<g6(8192, DD), blk8, 0, stream>>>(Sc, CVt, nullptr, R4 + 1536, nullptr,
      8, 512, 512, 3072, 1.f, 12, (size_t)DD * 512, 0, 0, 0);

  // merged out = x + concat @ [Wo;CWo] + (bo+Cbo)
  T(Wo, R1, DD, DD, nullptr, 3072);
  T(CWo, R1 + 1536, DD, DD, nullptr, 3072);
  gemm8<EPI_ADD_X, 3><<<g6(8192, DD), blk8, 0, stream>>>(R4, R1, biasm, out, x,
      48, 3072, 3072, DD, 1.f, 0, 0, 0, 0, 0);

  // FFN: LN -> W1+gelu (single N=6144) -> W2 (single K=6144) acc
  norm_ln<<<8192, blk, 0, stream>>>(x, lnw, lnb, R2);
  T(W1, R0, DD, FF, nullptr, DD);
  gemm8<EPI_GELU, 4><<<g8(8192, FF), blk8, 0, stream>>>(R2, R0, b1, H, nullptr,
      24, DD, DD, FF, 1.f, 0, 0, 0, 0, 0);
  T(W2, R1, FF, DD, nullptr, FF);
  gemm8<EPI_ACC, 3><<<g6(8192, DD), blk8, 0, stream>>>(H, R1, b2, out, nullptr,
      96, FF, FF, DD, 1.f, 0, 0, 0, 0, 0);
}

// Round 22
// 1040.221 us; speedup vs baseline: 1.0221x; 1.0221x over previous
//
#include <hip/hip_runtime.h>
#include <hip/hip_bf16.h>
#include <cmath>

#define DD 1536
#define FF 6144

typedef __bf16 bf16_t;
typedef __bf16 bf16x8 __attribute__((ext_vector_type(8)));
typedef __bf16 bf16x4 __attribute__((ext_vector_type(4)));
typedef float  f32x4  __attribute__((ext_vector_type(4)));

#define VM0 asm volatile("s_waitcnt vmcnt(0)" ::: "memory")
#define SB  __builtin_amdgcn_sched_barrier(0)
#define LGKM(N) do { asm volatile("s_waitcnt lgkmcnt(" #N ")" :::); SB; } while (0)
#define BAR __builtin_amdgcn_s_barrier()

__device__ __forceinline__ void async_load16(const bf16_t* g, bf16_t* l) {
  __builtin_amdgcn_global_load_lds(
      (const __attribute__((address_space(1))) void*)g,
      (__attribute__((address_space(3))) void*)l, 16, 0, 0);
}

// inline-asm LDS read: NOT ordered vs global_load_lds by the compiler; ordering is
// done explicitly via {vmcnt; barrier} (RAW) and counted lgkmcnt + sched_barrier (use).
__device__ __forceinline__ bf16x8 ds_read128(unsigned int addr) {
  bf16x8 r;
  asm volatile("ds_read_b128 %0, %1" : "=v"(r) : "v"(addr));
  return r;
}

// bijective XCD-aware remap (m204)
__device__ __forceinline__ void xcd_remap(int& bx, int& by) {
  const int gx = gridDim.x, gy = gridDim.y;
  int wg = by * gx + bx;
  const int nwg = gx * gy;
  const int q = nwg >> 3, r = nwg & 7, xcd = wg & 7, o = wg >> 3;
  wg = (xcd < r ? xcd * (q + 1) : r * (q + 1) + (xcd - r) * q) + o;
  bx = wg % gx;
  by = wg / gx;
}

// ---------------- weight fp32 -> bf16 transpose; optional per-K scale; output row stride ldt
__global__ __launch_bounds__(256) void transpose_to_bf16(
    const float* __restrict__ W, bf16_t* __restrict__ Wt, int K, int N,
    const float* __restrict__ s, int ldt) {
  __shared__ float tile[32][33];
  const int tx = threadIdx.x, ty = threadIdx.y;  // 32 x 8
  const int n0 = blockIdx.x * 32, k0 = blockIdx.y * 32;
#pragma unroll
  for (int i = 0; i < 4; i++)
    tile[ty + 8 * i][tx] = W[(size_t)(k0 + ty + 8 * i) * N + n0 + tx];
  __syncthreads();
  const float sc = (s != nullptr) ? s[k0 + tx] : 1.f;
#pragma unroll
  for (int i = 0; i < 4; i++)
    Wt[(size_t)(n0 + ty + 8 * i) * ldt + k0 + tx] = (bf16_t)(tile[tx][ty + 8 * i] * sc);
}

// ---------------- biasm = a + b ----------------
__global__ __launch_bounds__(256) void bias_add2(
    const float* __restrict__ a, const float* __restrict__ b, float* __restrict__ o, int n) {
  const int i = blockIdx.x * 256 + threadIdx.x;
  if (i < n) o[i] = a[i] + b[i];
}

// ---------------- reduction helpers ----------------
__device__ __forceinline__ void breduce1(float& a) {
#pragma unroll
  for (int off = 32; off; off >>= 1) a += __shfl_xor(a, off);
  __shared__ float sa[4];
  const int w = threadIdx.x >> 6, ln = threadIdx.x & 63;
  if (ln == 0) sa[w] = a;
  __syncthreads();
  a = (sa[0] + sa[1]) + (sa[2] + sa[3]);
  __syncthreads();
}

__device__ __forceinline__ void breduce2(float& a, float& b) {
#pragma unroll
  for (int off = 32; off; off >>= 1) {
    a += __shfl_xor(a, off);
    b += __shfl_xor(b, off);
  }
  __shared__ float sa[4], sb[4];
  const int w = threadIdx.x >> 6, ln = threadIdx.x & 63;
  if (ln == 0) { sa[w] = a; sb[w] = b; }
  __syncthreads();
  a = (sa[0] + sa[1]) + (sa[2] + sa[3]);
  b = (sb[0] + sb[1]) + (sb[2] + sb[3]);
  __syncthreads();
}

// ---------------- x: xr = x*rq (bf16) + rqinv[row] = sqrt(ms+eps) ----------------
__global__ __launch_bounds__(256) void norm_x1(
    const float* __restrict__ x, bf16_t* __restrict__ xr, float* __restrict__ rqinv) {
  const int row = blockIdx.x, t = threadIdx.x;
  const float* p = x + (size_t)row * DD;
  f32x4 v0 = ((const f32x4*)p)[t];
  f32x4 v1 = 0.0f;
  if (t < 128) v1 = ((const f32x4*)p)[256 + t];
  float s2 = 0.f;
#pragma unroll
  for (int e = 0; e < 4; e++) s2 += v0[e] * v0[e];
  if (t < 128) {
#pragma unroll
    for (int e = 0; e < 4; e++) s2 += v1[e] * v1[e];
  }
  breduce1(s2);
  const float ms = s2 * (1.f / DD) + 1e-7f;
  const float rq = rsqrtf(ms);
  if (t == 0) rqinv[row] = sqrtf(ms);
  auto emit = [&](int ci, f32x4 v) {
    bf16x4 orr;
#pragma unroll
    for (int e = 0; e < 4; e++) orr[e] = (bf16_t)(v[e] * rq);
    *(bf16x4*)(xr + (size_t)row * DD + ci * 4) = orr;
  };
  emit(t, v0);
  if (t < 128) emit(256 + t, v1);
}

// ---------------- LayerNorm -> bf16 ----------------
__global__ __launch_bounds__(256) void norm_ln(
    const float* __restrict__ x, const float* __restrict__ w,
    const float* __restrict__ bb, bf16_t* __restrict__ o) {
  const int row = blockIdx.x, t = threadIdx.x;
  const float* p = x + (size_t)row * DD;
  f32x4 v0 = ((const f32x4*)p)[t];
  f32x4 v1 = 0.0f;
  if (t < 128) v1 = ((const f32x4*)p)[256 + t];
  float s = 0.f, s2 = 0.f;
#pragma unroll
  for (int e = 0; e < 4; e++) { s += v0[e]; s2 += v0[e] * v0[e]; }
  if (t < 128) {
#pragma unroll
    for (int e = 0; e < 4; e++) { s += v1[e]; s2 += v1[e] * v1[e]; }
  }
  breduce2(s, s2);
  const float mu = s * (1.f / DD);
  const float rln = rsqrtf(s2 * (1.f / DD) - mu * mu + 1e-5f);
  auto emit = [&](int ci, f32x4 v) {
    const int i0 = ci * 4;
    bf16x4 ov;
#pragma unroll
    for (int e = 0; e < 4; e++)
      ov[e] = (bf16_t)((v[e] - mu) * rln * w[i0 + e] + bb[i0 + e]);
    *(bf16x4*)(o + (size_t)row * DD + i0) = ov;
  };
  emit(t, v0);
  if (t < 128) emit(256 + t, v1);
}

// ---------------- text: Tb = raw bf16, Tck = text*rtq ----------
__global__ __launch_bounds__(256) void norm_t2(
    const float* __restrict__ te, bf16_t* __restrict__ tb, bf16_t* __restrict__ tck) {
  const int row = blockIdx.x, t = threadIdx.x;
  const float* p = te + (size_t)row * DD;
  f32x4 v0 = ((const f32x4*)p)[t];
  f32x4 v1 = 0.0f;
  if (t < 128) v1 = ((const f32x4*)p)[256 + t];
  float s2 = 0.f;
#pragma unroll
  for (int e = 0; e < 4; e++) s2 += v0[e] * v0[e];
  if (t < 128) {
#pragma unroll
    for (int e = 0; e < 4; e++) s2 += v1[e] * v1[e];
  }
  breduce1(s2);
  const float rq = rsqrtf(s2 * (1.f / DD) + 1e-7f);
  auto emit = [&](int ci, f32x4 v) {
    bf16x4 ob, oc;
#pragma unroll
    for (int e = 0; e < 4; e++) {
      ob[e] = (bf16_t)v[e];
      oc[e] = (bf16_t)(v[e] * rq);
    }
    const size_t o = (size_t)row * DD + ci * 4;
    *(bf16x4*)(tb + o) = ob;
    *(bf16x4*)(tck + o) = oc;
  };
  emit(t, v0);
  if (t < 128) emit(256 + t, v1);
}

// ---------------- in-place bf16 row softmax ----------------
template <int NC>
__global__ __launch_bounds__(256) void softmax_bf16(bf16_t* __restrict__ S) {
  const int t = threadIdx.x;
  bf16_t* sr = S + (size_t)blockIdx.x * NC;
  constexpr int NV = (NC / 8 + 255) / 256;
  float v[NV][8];
  float mx = -3.4e38f;
#pragma unroll
  for (int i = 0; i < NV; i++) {
    const int idx = t + i * 256;
    if (idx * 8 < NC) {
      bf16x8 b = ((const bf16x8*)sr)[idx];
#pragma unroll
      for (int e = 0; e < 8; e++) {
        v[i][e] = (float)b[e];
        mx = fmaxf(mx, v[i][e]);
      }
    }
  }
#pragma unroll
  for (int off = 32; off; off >>= 1) mx = fmaxf(mx, __shfl_xor(mx, off));
  __shared__ float sm[4];
  const int w = t >> 6, ln = t & 63;
  if (ln == 0) sm[w] = mx;
  __syncthreads();
  mx = fmaxf(fmaxf(sm[0], sm[1]), fmaxf(sm[2], sm[3]));
  __syncthreads();
  float sum = 0.f;
#pragma unroll
  for (int i = 0; i < NV; i++) {
    const int idx = t + i * 256;
    if (idx * 8 < NC) {
#pragma unroll
      for (int e = 0; e < 8; e++) {
        v[i][e] = __expf(v[i][e] - mx);
        sum += v[i][e];
      }
    }
  }
#pragma unroll
  for (int off = 32; off; off >>= 1) sum += __shfl_xor(sum, off);
  __shared__ float ss[4];
  if (ln == 0) ss[w] = sum;
  __syncthreads();
  sum = (ss[0] + ss[1]) + (ss[2] + ss[3]);
  const float inv = 1.f / sum;
#pragma unroll
  for (int i = 0; i < NV; i++) {
    const int idx = t + i * 256;
    if (idx * 8 < NC) {
      bf16x8 o;
#pragma unroll
      for (int e = 0; e < 8; e++) o[e] = (bf16_t)(v[i][e] * inv);
      ((bf16x8*)sr)[idx] = o;
    }
  }
}

enum { EPI_BF16 = 0, EPI_F32_SCALE = 1, EPI_ADD_X = 2, EPI_ACC = 3, EPI_GELU = 4, EPI_TRANS = 5, EPI_BF16S = 6, EPI_PROJ3 = 7 };

template <int EPI>
__device__ __forceinline__ void epi_frag(
    f32x4 v, int r0, int c, const float* bias, void* Cout, const float* Xres,
    int ldc, float scale, int t_ld, int t_bshift, size_t t_bstride) {
  const float bv = (bias != nullptr) ? bias[c] : 0.f;
  if constexpr (EPI == EPI_BF16) {
    bf16_t* C = (bf16_t*)Cout;
#pragma unroll
    for (int r = 0; r < 4; r++) C[(size_t)(r0 + r) * ldc + c] = (bf16_t)(v[r] + bv);
  } else if constexpr (EPI == EPI_F32_SCALE) {
    float* C = (float*)Cout;
#pragma unroll
    for (int r = 0; r < 4; r++) C[(size_t)(r0 + r) * ldc + c] = v[r] * scale;
  } else if constexpr (EPI == EPI_BF16S) {
    bf16_t* C = (bf16_t*)Cout;
#pragma unroll
    for (int r = 0; r < 4; r++) C[(size_t)(r0 + r) * ldc + c] = (bf16_t)(v[r] * scale);
  } else if constexpr (EPI == EPI_ADD_X) {
    float* C = (float*)Cout;
#pragma unroll
    for (int r = 0; r < 4; r++) {
      const size_t ix = (size_t)(r0 + r) * ldc + c;
      C[ix] = Xres[ix] + v[r] + bv;
    }
  } else if constexpr (EPI == EPI_ACC) {
    float* C = (float*)Cout;
#pragma unroll
    for (int r = 0; r < 4; r++) {
      const size_t ix = (size_t)(r0 + r) * ldc + c;
      C[ix] += v[r] + bv;
    }
  } else if constexpr (EPI == EPI_GELU) {
    bf16_t* C = (bf16_t*)Cout;
#pragma unroll
    for (int r = 0; r < 4; r++) {
      const float h = v[r] + bv;
      C[(size_t)(r0 + r) * ldc + c] = (bf16_t)(0.5f * h * (1.f + erff(h * 0.70710678118654752f)));
    }
  } else if constexpr (EPI == EPI_TRANS) {  // batched C^T: out[b][c][n]
    const int b = r0 >> t_bshift;
    const int n = r0 & ((1 << t_bshift) - 1);
    bf16_t* C = (bf16_t*)Cout + (size_t)b * t_bstride + (size_t)c * t_ld + n;
    bf16x4 o;
#pragma unroll
    for (int r = 0; r < 4; r++) o[r] = (bf16_t)(v[r] + bv);
    *(bf16x4*)C = o;
  } else {  // EPI_PROJ3: mega-projection. Cout=R4 (QK base, ldc 3072); arena-contiguous
            // Vt = Cout+25165824 (V^T batched, ld 4096), CQ = Cout+37748736 (ldc 1536).
            // Xres = rqinv[row] (per-row inverse rms factor, applied to V region only).
    bf16_t* base = (bf16_t*)Cout;
    if (c < 1536) {          // V^T with per-row descale
      const int b = r0 >> 12, n = r0 & 4095;
      bf16_t* C = base + 25165824 + (size_t)b * ((size_t)DD * 4096) + (size_t)c * 4096 + n;
      bf16x4 o;
#pragma unroll
      for (int r = 0; r < 4; r++) o[r] = (bf16_t)(v[r] * Xres[r0 + r] + bv);
      *(bf16x4*)C = o;
    } else if (c < 4608) {   // Q|K row-major, ldc 3072
#pragma unroll
      for (int r = 0; r < 4; r++) base[(size_t)(r0 + r) * 3072 + (c - 1536)] = (bf16_t)(v[r] + bv);
    } else {                 // CQ row-major, ldc 1536
      bf16_t* C = base + 37748736;
#pragma unroll
      for (int r = 0; r < 4; r++) C[(size_t)(r0 + r) * 1536 + (c - 4608)] = (bf16_t)(v[r] + bv);
    }
  }
}

// ---------------- gemm_bt: 128x128 tile, 4 waves, BK=32 (proven r2 kernel + batch-B) ------
template <int EPI>
__global__ __launch_bounds__(256) void gemm_bt(
    const bf16_t* __restrict__ A, const bf16_t* __restrict__ B,
    const float* __restrict__ bias, void* __restrict__ Cout,
    const float* __restrict__ Xres,
    int nK, int lda, int ldb, int ldc, float scale,
    int bsh, size_t bstr, int t_ld, int t_bshift, size_t t_bstride) {
  __shared__ __align__(16) bf16_t As[2][128 * 32];
  __shared__ __align__(16) bf16_t Bs[2][128 * 32];
  const int tid = threadIdx.x;
  int bx = blockIdx.x, by = blockIdx.y;
  xcd_remap(bx, by);
  const int m0 = by * 128, n0 = bx * 128;
  const int wave = tid >> 6, lane = tid & 63, l15 = lane & 15, hi = lane >> 4;
  const int wm = wave >> 1, wn = wave & 1;
  const int srow = tid >> 2, scol = (tid & 3) << 3;

  const bf16_t* Bb = bsh ? (B + (size_t)(m0 >> bsh) * bstr) : B;
  const bf16_t* ga = A + (size_t)(m0 + srow) * lda + scol;
  const bf16_t* gb = Bb + (size_t)(n0 + srow) * ldb + scol;
  const int lo = wave * 512;

  f32x4 acc[4][4];
#pragma unroll
  for (int i = 0; i < 4; i++)
#pragma unroll
    for (int j = 0; j < 4; j++) acc[i][j] = 0.0f;

  auto stage = [&](int buf, int kt) {
    const bf16_t* a = ga + (size_t)kt * 32;
    const bf16_t* b = gb + (size_t)kt * 32;
    async_load16(a, &As[buf][lo]);
    async_load16(a + (size_t)64 * lda, &As[buf][2048 + lo]);
    async_load16(b, &Bs[buf][lo]);
    async_load16(b + (size_t)64 * ldb, &Bs[buf][2048 + lo]);
  };

  auto compute = [&](int buf) {
    bf16x8 af[4], bg[4];
#pragma unroll
    for (int i = 0; i < 4; i++)
      af[i] = *(const bf16x8*)&As[buf][(wm * 64 + i * 16 + l15) * 32 + hi * 8];
#pragma unroll
    for (int j = 0; j < 4; j++)
      bg[j] = *(const bf16x8*)&Bs[buf][(wn * 64 + j * 16 + l15) * 32 + hi * 8];
#pragma unroll
    for (int i = 0; i < 4; i++)
#pragma unroll
      for (int j = 0; j < 4; j++)
        acc[i][j] = __builtin_amdgcn_mfma_f32_16x16x32_bf16(af[i], bg[j], acc[i][j], 0, 0, 0);
  };

  stage(0, 0);
  __syncthreads();
  for (int kt = 0; kt < nK; ++kt) {
    if (kt + 1 < nK) stage((kt + 1) & 1, kt + 1);
    compute(kt & 1);
    __syncthreads();
  }

#pragma unroll
  for (int i = 0; i < 4; i++) {
    const int r0 = m0 + wm * 64 + i * 16 + hi * 4;
#pragma unroll
    for (int j = 0; j < 4; j++) {
      const int c = n0 + wn * 64 + j * 16 + l15;
      epi_frag<EPI>(acc[i][j], r0, c, bias, Cout, Xres, ldc, scale, t_ld, t_bshift, t_bstride);
    }
  }
}

// ---------------- gemm8: 256 x (NF*64) tile, 8 waves, BK=64, single-barrier K-tile --------
// NF = N-fragments per wave (wave tile = 128 x NF*16; block N = NF*64).
//   NF=4: 256-wide tile, byte-exact r15 schedule (verified 1098us baseline).
//   NF=3: 192-wide tile -> N=1536 grids become 32x8 = 256 blocks = 100% CU fill
//         (r15's 256-wide tile gave 192 blocks = 75% fill on PV/out/W2).
// Ledger (identical to r15): RAW: per-wave VM0 drains own tile-k DMA (issued last
// iter, full body in flight); BAR globalizes (r6 lesson). WAR: every wave's
// prev-iter ds_reads drained at its final LGKM(0) before entering BAR -> staging
// buf^1 after BAR is safe. Wave-row offsets (wn*NF*16) are multiples of 8 so the
// XOR-swizzle row term stays l15&7 on both write and read sides. Staging dests are
// wave-uniform (m104/m108; r16 lesson). acc[8][NF] <= 128 VGPR-equiv (r10 lesson).
template <int EPI, int NF>
__global__ __launch_bounds__(512, 2) void gemm8(
    const bf16_t* __restrict__ A, const bf16_t* __restrict__ B,
    const float* __restrict__ bias, void* __restrict__ Cout,
    const float* __restrict__ Xres,
    int nT, int lda, int ldb, int ldc, float scale,
    int bsh, size_t bstr, int t_ld, int t_bshift, size_t t_bstride) {
  constexpr int NB = NF * 64;   // B-tile rows (output cols per block)
  __shared__ __align__(16) bf16_t As[2][256 * 64];
  __shared__ __align__(16) bf16_t Bs[2][NB * 64];
  const int tid = threadIdx.x;
  int bx = blockIdx.x, by = blockIdx.y;
  xcd_remap(bx, by);
  const int m0 = by * 256, n0 = bx * NB;
  const int wave = tid >> 6, lane = tid & 63, l15 = lane & 15, hi = lane >> 4;
  const int wm = wave >> 2, wn = wave & 3;  // 2 x 4 waves; per-wave 128 x NF*16 output

  const int srow = tid >> 3;
  const int scol = ((tid & 7) ^ (srow & 7)) << 3;
  const bf16_t* Bb = bsh ? (B + (size_t)(m0 >> bsh) * bstr) : B;
  const bf16_t* gA = A + (size_t)(m0 + srow) * lda + scol;
  const bf16_t* gB = Bb + (size_t)(n0 + srow) * ldb + scol;
  const int ldst = wave * 512;

  // per-lane ds_read byte bases (buf 0); A buf1 = +32768, B buf1 = +NF*8192
  const unsigned swz0 = (unsigned)(((hi ^ (l15 & 7)) << 3) * 2);
  const unsigned swz1 = (unsigned)((((hi + 4) ^ (l15 & 7)) << 3) * 2);
  const unsigned aBase = (unsigned)(size_t)&As[0][0] + (unsigned)((wm * 128 + l15) * 128);
  const unsigned bBase = (unsigned)(size_t)&Bs[0][0] + (unsigned)((wn * NF * 16 + l15) * 128);
  const unsigned a0 = aBase + swz0, a1 = aBase + swz1;
  const unsigned b0 = bBase + swz0, b1 = bBase + swz1;

  f32x4 acc[8][NF];
#pragma unroll
  for (int i = 0; i < 8; i++)
#pragma unroll
    for (int j = 0; j < NF; j++) acc[i][j] = 0.0f;

  auto stgA = [&](int t) {
    if (t >= nT) return;
    const int buf = t & 1;
    const size_t kof = (size_t)t * 64;
#pragma unroll
    for (int g = 0; g < 4; g++)
      async_load16(gA + (size_t)(g * 64) * lda + kof, &As[buf][g * 4096 + ldst]);
  };
  auto stgB = [&](int t) {
    if (t >= nT) return;
    const int buf = t & 1;
    const size_t kof = (size_t)t * 64;
#pragma unroll
    for (int g = 0; g < NF; g++)
      async_load16(gB + (size_t)(g * 64) * ldb + kof, &Bs[buf][g * 4096 + ldst]);
  };

  bf16x8 af[4][2], bg[NF][2];
  auto LDA = [&](int buf, int mh) {
#pragma unroll
    for (int i = 0; i < 4; i++) {
      const unsigned d = (unsigned)(buf * 32768 + (mh * 4 + i) * 2048);
      af[i][0] = ds_read128(a0 + d);
      af[i][1] = ds_read128(a1 + d);
    }
  };
  auto LDBf = [&](int buf, int fj) {
    const unsigned d = (unsigned)(buf * (NF * 8192) + fj * 2048);
    bg[fj][0] = ds_read128(b0 + d);
    bg[fj][1] = ds_read128(b1 + d);
  };
  auto MMf = [&](int mh, int fj) {
    __builtin_amdgcn_s_setprio(1);
#pragma unroll
    for (int i = 0; i < 4; i++)
#pragma unroll
      for (int ks = 0; ks < 2; ks++)
        acc[mh * 4 + i][fj] = __builtin_amdgcn_mfma_f32_16x16x32_bf16(
            af[i][ks], bg[fj][ks], acc[mh * 4 + i][fj], 0, 0, 0);
    __builtin_amdgcn_s_setprio(0);
  };

  // one K-tile iteration; buf is a compile-time literal at each call site
  auto iter = [&](int k, int buf) {
    VM0;   // per-wave: own tile-k loads (issued last iter) drained
    BAR;   // globalize drain (RAW) + all waves' buf^1 reads done (WAR)
    stgB(k + 1);
    stgA(k + 1);
    LDA(buf, 0);
#pragma unroll
    for (int fj = 0; fj < NF; fj++) LDBf(buf, fj);
    SB;
    if constexpr (NF == 4) {  // byte-exact r15 wait sequence
      LGKM(4);  MMf(0, 0); MMf(0, 1);
      LGKM(0);  MMf(0, 2); MMf(0, 3);
    } else {                  // NF == 3: same ledger, finer counted waits
      LGKM(4);  MMf(0, 0);
      LGKM(2);  MMf(0, 1);
      LGKM(0);  MMf(0, 2);
    }
    LDA(buf, 1);   // re-issue af <- mh1 (consumers of af0 already issued)
    SB;
    LGKM(0);
#pragma unroll
    for (int fj = 0; fj < NF; fj++) MMf(1, fj);
  };

  // prologue: stage tile 0
  stgB(0);
  stgA(0);

  for (int k = 0; k < nT; k += 2) {  // nT is even for all call sites
    iter(k, 0);
    iter(k + 1, 1);
  }

#pragma unroll
  for (int fi = 0; fi < 8; fi++) {
    const int r0 = m0 + wm * 128 + fi * 16 + hi * 4;
#pragma unroll
    for (int fj = 0; fj < NF; fj++) {
      const int c = n0 + wn * NF * 16 + fj * 16 + l15;
      epi_frag<EPI>(acc[fi][fj], r0, c, bias, Cout, Xres, ldc, scale, t_ld, t_bshift, t_bstride);
    }
  }
}

// ---------------- host ----------------
extern "C" void kernel_launch(void* const* d_in, const int* in_sizes, int n_in,
                              void* d_out, int out_size, void* d_ws, size_t ws_size,
                              hipStream_t stream) {
  (void)in_sizes; (void)n_in; (void)out_size; (void)ws_size;
  const float* x   = (const float*)d_in[0];
  const float* te  = (const float*)d_in[1];
  const float* sqw = (const float*)d_in[2];
  const float* skw = (const float*)d_in[3];
  const float* cqw = (const float*)d_in[4];
  const float* ckw = (const float*)d_in[5];
  const float* lnw = (const float*)d_in[6];
  const float* lnb = (const float*)d_in[7];
  const float* Wq = (const float*)d_in[8];  const float* bq = (const float*)d_in[9];
  const float* Wk = (const float*)d_in[10]; const float* bk = (const float*)d_in[11];
  const float* Wv = (const float*)d_in[12]; const float* bv = (const float*)d_in[13];
  const float* Wo = (const float*)d_in[14]; const float* bo = (const float*)d_in[15];
  const float* CWq = (const float*)d_in[16]; const float* Cbq = (const float*)d_in[17];
  const float* CWk = (const float*)d_in[18]; const float* Cbk = (const float*)d_in[19];
  const float* CWv = (const float*)d_in[20]; const float* Cbv = (const float*)d_in[21];
  const float* CWo = (const float*)d_in[22]; const float* Cbo = (const float*)d_in[23];
  const float* W1 = (const float*)d_in[24]; const float* b1 = (const float*)d_in[25];
  const float* W2 = (const float*)d_in[26]; const float* b2 = (const float*)d_in[27];
  float* out = (float*)d_out;

  // ---- arena (bf16 el offsets); peak ~170 MB ----
  bf16_t* ws = (bf16_t*)d_ws;
  bf16_t* R0 = ws;                  // 9437184: [Wv|Wq|Wk|CWq]^T -> {CK,CVt,Sc} -> W1^T
  bf16_t* R1 = ws + 9437184;        // 9437184: CWk/CWv^T -> [Wo|CWo]^T -> W2^T
  bf16_t* R2 = ws + 18874368;       // 12582912: xr -> LNo
  bf16_t* Tb  = ws + 31457280;      // 1572864
  bf16_t* Tck = ws + 33030144;      // 1572864
  bf16_t* R4 = ws + 34603008;       // 25165824: Q|K(ldc3072) -> concat APre|CPre -> H[0:..]
  bf16_t* R5 = ws + 59768832;       // 12582912: V^T -> H mid   (= R4 + 25165824)
  bf16_t* R6 = ws + 72351744;       // 12582912: CQ -> H end    (= R4 + 37748736)
  bf16_t* S  = ws;                  // 33554432 overlay (self-attn scores)
  float* bcat4 = (float*)(ws + 84934656);    // 6144 f32 = [bv|bq|bk|Cbq]
  float* biasm = (float*)(ws + 84946944);    // 1536 f32 = bo+Cbo
  float* rqinv = (float*)(ws + 84950016);    // 8192 f32
  bf16_t* CK  = R0;
  bf16_t* CVt = R0 + 1572864;
  bf16_t* Sc  = R0 + 3145728;       // 8192x512 bf16
  bf16_t* H   = R4;                 // 8192x6144 (R4+R5+R6 contiguous)

  const dim3 blk(256), blk8(512), tb(32, 8);
  const float scl = 0.025515518153991442f;  // 1/sqrt(1536)

  auto T = [&](const float* W, bf16_t* Wt, int K, int N, const float* s, int ldt) {
    transpose_to_bf16<<<dim3(N / 32, K / 32), tb, 0, stream>>>(W, Wt, K, N, s, ldt);
  };
  auto g8 = [](int M, int N) { return dim3(N / 256, M / 256); };   // NF=4 grids
  auto g6 = [](int M, int N) { return dim3(N / 192, M / 256); };   // NF=3 grids
  auto g4 = [](int M, int N) { return dim3(N / 128, M / 128); };

  // biases
  hipMemcpyAsync(bcat4,        bv,  DD * sizeof(float), hipMemcpyDeviceToDevice, stream);
  hipMemcpyAsync(bcat4 + DD,   bq,  DD * sizeof(float), hipMemcpyDeviceToDevice, stream);
  hipMemcpyAsync(bcat4 + 2*DD, bk,  DD * sizeof(float), hipMemcpyDeviceToDevice, stream);
  hipMemcpyAsync(bcat4 + 3*DD, Cbq, DD * sizeof(float), hipMemcpyDeviceToDevice, stream);
  bias_add2<<<6, blk, 0, stream>>>(bo, Cbo, biasm, DD);

  // norm: xr + per-row descale
  norm_x1<<<8192, blk, 0, stream>>>(x, R2, rqinv);

  // mega-projection: [V^T | Q|K | CQ] = xr @ [Wv | Wq*sqw | Wk*skw | CWq*cqw]^T, N=6144
  T(Wv,  R0,               DD, DD, nullptr, DD);
  T(Wq,  R0 + 2359296,     DD, DD, sqw,     DD);
  T(Wk,  R0 + 4718592,     DD, DD, skw,     DD);
  T(CWq, R0 + 7077888,     DD, DD, cqw,     DD);
  gemm8<EPI_PROJ3, 4><<<g8(8192, FF), blk8, 0, stream>>>(R2, R0, bcat4, R4, rqinv,
      24, DD, DD, 3072, 1.f, 0, 0, 0, 0, 0);

  // self-attention (batched over 2 via m0>>12)
  gemm8<EPI_BF16S, 4><<<g8(8192, 4096), blk8, 0, stream>>>(R4 /*Q*/, R4 + DD /*K*/, nullptr, S, nullptr,
      24, 3072, 3072, 4096, scl, 12, (size_t)4096 * 3072, 0, 0, 0);
  softmax_bf16<4096><<<8192, blk, 0, stream>>>(S);
  gemm8<EPI_BF16, 3><<<g6(8192, DD), blk8, 0, stream>>>(S, R5, nullptr, R4, nullptr,
      64, 4096, 4096, 3072, 1.f, 12, (size_t)DD * 4096, 0, 0, 0);

  // cross-attention
  norm_t2<<<1024, blk, 0, stream>>>(te, Tb, Tck);
  T(CWk, R1, DD, DD, ckw, DD);
  gemm_bt<EPI_BF16><<<g4(1024, DD), blk, 0, stream>>>(Tck, R1, Cbk, CK, nullptr,
      48, DD, DD, DD, 1.f, 0, 0, 0, 0, 0);
  T(CWv, R1 + 2359296, DD, DD, nullptr, DD);
  gemm_bt<EPI_TRANS><<<g4(1024, DD), blk, 0, stream>>>(Tb, R1 + 2359296, Cbv, CVt, nullptr,
      48, DD, DD, 0, 1.f, 0, 0, 512, 9, (size_t)DD * 512);
  gemm_bt<EPI_BF16S><<<g4(8192, 512), blk, 0, stream>>>(R6 /*CQ*/, CK, nullptr, Sc, nullptr,
      48, DD, DD, 512, scl, 12, (size_t)512 * DD, 0, 0, 0);
  softmax_bf16<512><<<8192, blk, 0, stream>>>(Sc);
  gemm8<EPI_BF16, 3><<<g6(8192, DD), blk8, 0, stream>>>(Sc, CVt, nullptr, R4 + 1536, nullptr,
      8, 512, 512, 3072, 1.f, 12, (size_t)DD * 512, 0, 0, 0);

  // merged out = x + concat @ [Wo;CWo] + (bo+Cbo)
  T(Wo, R1, DD, DD, nullptr, 3072);
  T(CWo, R1 + 1536, DD, DD, nullptr, 3072);
  gemm8<EPI_ADD_X, 3><<<g6(8192, DD), blk8, 0, stream>>>(R4, R1, biasm, out, x,
      48, 3072, 3072, DD, 1.f, 0, 0, 0, 0, 0);

  // FFN: LN -> W1+gelu (single N=6144) -> W2 (single K=6144) acc
  norm_ln<<<8192, blk, 0, stream>>>(x, lnw, lnb, R2);
  T(W1, R0, DD, FF, nullptr, DD);
  gemm8<EPI_GELU, 4><<<g8(8192, FF), blk8, 0, stream>>>(R2, R0, b1, H, nullptr,
      24, DD, DD, FF, 1.f, 0, 0, 0, 0, 0);
  T(W2, R1, FF, DD, nullptr, FF);
  gemm8<EPI_ACC, 3><<<g6(8192, DD), blk8, 0, stream>>>(H, R1, b2, out, nullptr,
      96, FF, FF, DD, 1.f, 0, 0, 0, 0, 0);
}